// Round 14
// baseline (524.084 us; speedup 1.0000x reference)
//
#include <hip/hip_runtime.h>

#define BB 8
#define CC 256
#define HH 128
#define WW 128
#define HW (HH*WW)

typedef float f32x4 __attribute__((ext_vector_type(4)));
typedef float f32x16 __attribute__((ext_vector_type(16)));
typedef short s16x8 __attribute__((ext_vector_type(8)));

__device__ inline unsigned short f2bf(float f) {
  union { float f; unsigned int u; } un;
  un.f = f;
  unsigned int u = un.u;
  return (unsigned short)((u + 0x7fffu + ((u >> 16) & 1u)) >> 16);  // RNE
}

__device__ __forceinline__ void gload_lds16(const void* g, void* l) {
  __builtin_amdgcn_global_load_lds(
      (const __attribute__((address_space(1))) unsigned int*)g,
      (__attribute__((address_space(3))) unsigned int*)l, 16, 0, 0);
}

// ---------------- kernel 0: x NCHW f32 -> xbf NHWC bf16 ----------------
__global__ __launch_bounds__(256) void k_prepass(const float* __restrict__ x,
                                                 unsigned short* __restrict__ xbf) {
  __shared__ float tile[64][68];
  int bh = blockIdx.x;
  int b = bh >> 7, h = bh & 127;
  int w0 = blockIdx.y * 64;
  int c0 = blockIdx.z * 64;
  int t = threadIdx.x;
  {
    int c = t >> 2, wq = (t & 3) << 4;
    const float4* src = reinterpret_cast<const float4*>(
        x + (((size_t)(b * CC + c0 + c) * HH + h) * WW + w0 + wq));
    float4 v0 = src[0], v1 = src[1], v2 = src[2], v3 = src[3];
    *reinterpret_cast<float4*>(&tile[c][wq + 0])  = v0;
    *reinterpret_cast<float4*>(&tile[c][wq + 4])  = v1;
    *reinterpret_cast<float4*>(&tile[c][wq + 8])  = v2;
    *reinterpret_cast<float4*>(&tile[c][wq + 12]) = v3;
  }
  __syncthreads();
  {
    int w = t >> 2, cg = (t & 3) << 4;
    unsigned short tmp[16];
#pragma unroll
    for (int i = 0; i < 16; ++i) tmp[i] = f2bf(tile[cg + i][w]);
    unsigned short* dst = xbf + ((size_t)(b * HH + h) * WW + w0 + w) * CC + c0 + cg;
    *reinterpret_cast<int4*>(dst)     = *reinterpret_cast<int4*>(tmp);
    *reinterpret_cast<int4*>(dst + 8) = *reinterpret_cast<int4*>(tmp + 8);
  }
}

// ------- kernel 1: weight repack -> [chunk8][tap9][foc768][ci32] bf16 + zeropage ----
__global__ __launch_bounds__(256) void k_repack(const float* __restrict__ Wq,
                                                const float* __restrict__ Wk,
                                                const float* __restrict__ Wv,
                                                unsigned short* __restrict__ Wp,
                                                unsigned short* __restrict__ zp) {
  if (blockIdx.x == 0 && threadIdx.x < 64) {
    int4 z = {0, 0, 0, 0};
    reinterpret_cast<int4*>(zp)[threadIdx.x] = z;   // 1 KB zero page
  }
  int idx = blockIdx.x * 256 + threadIdx.x;
  if (idx >= 8 * 9 * 768 * 32) return;
  int ci = idx & 31;
  int tmp = idx >> 5;
  int focs = tmp % 768;
  int tmp2 = tmp / 768;
  int tap = tmp2 % 9;
  int chunk = tmp2 / 9;
  int cv = focs >> 8, oc = focs & 255;
  int cin = chunk * 32 + ci;
  const float* Wsrc = (cv == 0) ? Wq : ((cv == 1) ? Wk : Wv);
  Wp[idx] = f2bf(Wsrc[(size_t)(oc * 256 + cin) * 9 + tap]);
}

// ------- kernel 2: fused QKV conv (R13 kernel, compiler-scheduled units) ------
// SINGLE CHANGE vs R13: removed the 48 intra-unit sched_barrier(0) walls and
// setprio toggles per chunk. Per unit the compiler now sees {16 BREAD, 3
// ALOAD, 2 stage, 24 MFMA} and can emit the m97-style fine interleave
// (ds_read between MFMAs + precise lgkmcnt counts). One wall per unit
// boundary bounds hoisting; chunk-boundary counted-vmcnt machinery unchanged.
__global__ __launch_bounds__(256, 2) void k_conv(const unsigned short* __restrict__ xbf,
                                                 const unsigned short* __restrict__ Wp,
                                                 const unsigned short* __restrict__ zp,
                                                 const float* __restrict__ bq,
                                                 const float* __restrict__ bk,
                                                 const float* __restrict__ bv,
                                                 unsigned short* __restrict__ qkv) {
  __shared__ unsigned short xs[2][4][132][32];
  __shared__ float bias_s[128];
  int bid = blockIdx.x;
  int v_ = (bid & 7) * 384 + (bid >> 3);   // bijective XCD swizzle (3072%8==0)
  int mtile = v_ % 6;                      // mtile fast (verified order)
  int bhp = v_ / 6;
  int b = bhp >> 6;
  int h0 = (bhp & 63) * 2;
  int t = threadIdx.x;
  int lane = t & 63, wave = t >> 6;
  int fq = wave;                           // foc-quarter; also staging row
  int l31 = lane & 31, lg1 = lane >> 5;

  if (t < 128) {
    int focs = mtile * 128 + t;
    int cv = focs >> 8, oc = focs & 255;
    const float* bp = (cv == 0) ? bq : ((cv == 1) ? bk : bv);
    bias_s[t] = bp[oc];
  }
  {  // zero the w-halo cells (wc = 0 and 129) of both buffers, all 4 rows
    int cell = t >> 4;
    int bf_ = cell >> 3, r_ = (cell >> 1) & 3;
    int wc_ = (cell & 1) ? 129 : 0;
    *reinterpret_cast<int*>(reinterpret_cast<char*>(&xs[bf_][r_][wc_][0]) + (t & 15) * 4) = 0;
  }

  // staging: lane covers col wc = 1 + l2 + j*16, quarter l4.
  // source oct = l4 ^ F'(wc); j*16 toggles F' by XOR 2 on odd j.
  int l2 = lane >> 2, l4 = lane & 3;
  int wcb = 1 + l2;
  int oswE = l4 ^ (((wcb >> 1) & 3) ^ ((wcb >> 3) & 3));   // even j
  int oswO = oswE ^ 2;                                     // odd j
  int hin = h0 + wave - 1;
  bool inb = ((unsigned)hin < 128u);
  const unsigned short* rowb =
      xbf + ((size_t)(b * HH + (inb ? hin : 0)) * WW + l2) * CC;
  const unsigned short* srowE = rowb + oswE * 8;
  const unsigned short* srowO = rowb + oswO * 8;
  const unsigned short* zsrc = zp + lane * 8;

  const size_t CH_STRIDE = (size_t)9 * 768 * 32;
  const unsigned short* apbase = Wp + (size_t)(mtile * 128 + fq * 32 + l31) * 32 + lg1 * 8;

  auto ALOAD = [&](s16x8 (&Af)[3], const unsigned short* ap, int un) {
    const int ss = un >> 1, kk = un & 1;
#pragma unroll
    for (int rr = 0; rr < 3; ++rr)
      Af[rr] = *reinterpret_cast<const s16x8*>(ap + (rr * 3 + ss) * (768 * 32) + kk * 16);
  };
  auto BREAD = [&](s16x8 (&Bf)[4], const char* xsb, int un, int nt) {
    const int ss = un >> 1, kk = un & 1;
    const int col = nt * 32 + l31 + ss;     // 0..129
    const int pslot = (kk * 2 + lg1) ^ (((col >> 1) & 3) ^ ((col >> 3) & 3));
#pragma unroll
    for (int rin = 0; rin < 4; ++rin)
      Bf[rin] = *reinterpret_cast<const s16x8*>(
          xsb + rin * (132 * 64) + col * 64 + pslot * 16);
  };

  f32x16 acc[2][4] = {};   // [row][nt]
  s16x8 Afb[2][3];         // A dbuf [unit&1][rr]
  s16x8 Bfb[2][4];         // B sub-cluster dbuf [nt&1][rin]

  // ---- prologue: stage chunk 0; A(u0); counted wait; barrier; B(u0,nt0)
  {
    char* d0 = reinterpret_cast<char*>(&xs[0][wave][1][0]);
    if (inb) {
#pragma unroll
      for (int j = 0; j < 8; ++j)
        gload_lds16(((j & 1) ? srowO : srowE) + j * (16 * CC), d0 + j * 1024);
    } else {
#pragma unroll
      for (int j = 0; j < 8; ++j) gload_lds16(zsrc, d0 + j * 1024);
    }
  }
  ALOAD(Afb[0], apbase, 0);
  asm volatile("s_waitcnt vmcnt(3)" ::: "memory");   // 8 stage retired (3 A newer)
  __builtin_amdgcn_s_barrier();
  BREAD(Bfb[0], reinterpret_cast<const char*>(&xs[0][0][0][0]), 0, 0);

  for (int chunk = 0; chunk < 8; ++chunk) {
    const int buf = chunk & 1;
    const unsigned short* ap_cur = apbase + chunk * CH_STRIDE;
    const char* xsb = reinterpret_cast<const char*>(&xs[buf][0][0][0]);

#pragma unroll
    for (int u = 0; u < 6; ++u) {
#pragma unroll
      for (int nt = 0; nt < 4; ++nt) {
        // ---- issue region (feeds the NEXT sub-cluster / unit)
        if (nt < 3) {
          BREAD(Bfb[(nt + 1) & 1], xsb, u, nt + 1);
        } else if (u < 5) {
          BREAD(Bfb[0], xsb, u + 1, 0);
        }
        if (nt == 0) {
          if (u < 5) ALOAD(Afb[(u + 1) & 1], ap_cur, u + 1);
          else if (chunk < 7) ALOAD(Afb[0], ap_cur + CH_STRIDE, 0);
          if (u < 4 && chunk < 7) {
            char* dstg = reinterpret_cast<char*>(&xs[buf ^ 1][wave][1][0]);
            int jA = 2 * u, jB = 2 * u + 1;     // jA even, jB odd
            if (inb) {
              gload_lds16(srowE + (size_t)(chunk + 1) * 32 + jA * (16 * CC), dstg + jA * 1024);
              gload_lds16(srowO + (size_t)(chunk + 1) * 32 + jB * (16 * CC), dstg + jB * 1024);
            } else {
              gload_lds16(zsrc, dstg + jA * 1024);
              gload_lds16(zsrc, dstg + jB * 1024);
            }
          }
        }
        // ---- sub-cluster: 6 MFMA (3 rr x 2 row); no walls, no setprio —
        // compiler interleaves reads/MFMA with precise lgkmcnt (m97 pattern)
#pragma unroll
        for (int rr = 0; rr < 3; ++rr)
#pragma unroll
          for (int row = 0; row < 2; ++row)
            acc[row][nt] = __builtin_amdgcn_mfma_f32_32x32x16_bf16(
                Afb[u & 1][rr], Bfb[nt & 1][row + rr], acc[row][nt], 0, 0, 0);
      }
      __builtin_amdgcn_sched_barrier(0);   // one wall per unit bounds hoisting
    }
    // ---- chunk boundary: counted drain (6 A-loads issued after last stage)
    if (chunk < 7) {
      asm volatile("s_waitcnt vmcnt(6)" ::: "memory");
      __builtin_amdgcn_s_barrier();
      asm volatile("" ::: "memory");
      BREAD(Bfb[0], reinterpret_cast<const char*>(&xs[buf ^ 1][0][0][0]), 0, 0);
    }
  }

  // epilogue: bias, relu (q,k), store bf16. D-layout 32x32:
  // col = lane&31, row = (reg&3) + 8*(reg>>2) + 4*(lane>>5)
#pragma unroll
  for (int row = 0; row < 2; ++row) {
#pragma unroll
    for (int nt = 0; nt < 4; ++nt) {
      int wcol = nt * 32 + l31;
      int h = h0 + row;
#pragma unroll
      for (int reg = 0; reg < 16; ++reg) {
        int rloc = (reg & 3) + 8 * (reg >> 2) + 4 * lg1;
        int floc = fq * 32 + rloc;
        float vv = acc[row][nt][reg] + bias_s[floc];
        int focs = mtile * 128 + floc;
        if (focs < 512) vv = fmaxf(vv, 0.0f);      // relu for q,k
        int cv = focs >> 8, oc = focs & 255;
        qkv[(size_t)(cv * 2048 + b * 256 + oc) * HW + h * WW + wcol] = f2bf(vv);
      }
    }
  }
}

// ---------------- kernel 3: per-(b,c) attention -------------------------------
// al aliases kt (kt dead after QK^T; barriers order last read before write).
#define PADA 136
__global__ __launch_bounds__(256) void k_attn(const unsigned short* __restrict__ qkv,
                                              const float* __restrict__ x,
                                              float* __restrict__ out) {
  __shared__ unsigned short kt[128][PADA];
  __shared__ unsigned short vt[128][PADA];
  __shared__ float red[8];
  unsigned short (*al)[PADA] = kt;    // alias: reuse kt after QK^T
  int bc = blockIdx.x;
  const unsigned short* qp = qkv + (size_t)bc * HW;
  const unsigned short* kp = qkv + (size_t)(2048 + bc) * HW;
  const unsigned short* vp = qkv + (size_t)(4096 + bc) * HW;
  int t = threadIdx.x;
  for (int g = t; g < HW; g += 256) {
    int row = g >> 7, col = g & 127;
    kt[col][row] = kp[g];
    vt[col][row] = vp[g];
  }
  __syncthreads();
  int lane = t & 63, wave = t >> 6;
  int wm = wave >> 1, wn = wave & 1;
  int l15 = lane & 15, lg = lane >> 4;
  f32x4 acc[4][4] = {};
#pragma unroll
  for (int kk = 0; kk < 4; ++kk) {
    s16x8 af[4], bfr[4];
#pragma unroll
    for (int m = 0; m < 4; ++m)
      af[m] = *reinterpret_cast<const s16x8*>(qp + (size_t)(wm * 64 + m * 16 + l15) * WW + kk * 32 + lg * 8);
#pragma unroll
    for (int n = 0; n < 4; ++n)
      bfr[n] = *reinterpret_cast<const s16x8*>(&kt[wn * 64 + n * 16 + l15][kk * 32 + lg * 8]);
#pragma unroll
    for (int m = 0; m < 4; ++m)
#pragma unroll
      for (int n = 0; n < 4; ++n)
        acc[m][n] = __builtin_amdgcn_mfma_f32_16x16x32_bf16(af[m], bfr[n], acc[m][n], 0, 0, 0);
  }
  float lm = -3.0e38f;
#pragma unroll
  for (int m = 0; m < 4; ++m)
#pragma unroll
    for (int n = 0; n < 4; ++n)
#pragma unroll
      for (int rg = 0; rg < 4; ++rg)
        lm = fmaxf(lm, acc[m][n][rg]);
  for (int off = 32; off > 0; off >>= 1) lm = fmaxf(lm, __shfl_xor(lm, off));
  if (lane == 0) red[wave] = lm;
  __syncthreads();   // also orders last kt read before al writes below
  float M = fmaxf(fmaxf(red[0], red[1]), fmaxf(red[2], red[3]));
  float ls = 0.0f;
#pragma unroll
  for (int m = 0; m < 4; ++m)
#pragma unroll
    for (int n = 0; n < 4; ++n)
#pragma unroll
      for (int rg = 0; rg < 4; ++rg)
        ls += __expf(acc[m][n][rg] - M);
  for (int off = 32; off > 0; off >>= 1) ls += __shfl_xor(ls, off);
  if (lane == 0) red[4 + wave] = ls;
  __syncthreads();
  float inv = 1.0f / (red[4] + red[5] + red[6] + red[7]);
#pragma unroll
  for (int m = 0; m < 4; ++m) {
#pragma unroll
    for (int n = 0; n < 4; ++n) {
      int col = wn * 64 + n * 16 + l15;
#pragma unroll
      for (int rg = 0; rg < 4; ++rg) {
        int row = wm * 64 + m * 16 + lg * 4 + rg;
        al[row][col] = f2bf(__expf(acc[m][n][rg] - M) * inv);
      }
    }
  }
  __syncthreads();
  f32x4 o_[4][4] = {};
#pragma unroll
  for (int kk = 0; kk < 4; ++kk) {
    s16x8 af[4], bfr[4];
#pragma unroll
    for (int m = 0; m < 4; ++m)
      af[m] = *reinterpret_cast<const s16x8*>(&al[wm * 64 + m * 16 + l15][kk * 32 + lg * 8]);
#pragma unroll
    for (int n = 0; n < 4; ++n)
      bfr[n] = *reinterpret_cast<const s16x8*>(&vt[wn * 64 + n * 16 + l15][kk * 32 + lg * 8]);
#pragma unroll
    for (int m = 0; m < 4; ++m)
#pragma unroll
      for (int n = 0; n < 4; ++n)
        o_[m][n] = __builtin_amdgcn_mfma_f32_16x16x32_bf16(af[m], bfr[n], o_[m][n], 0, 0, 0);
  }
  const float* xp = x + (size_t)bc * HW;
  float* op = out + (size_t)bc * HW;
#pragma unroll
  for (int m = 0; m < 4; ++m) {
#pragma unroll
    for (int n = 0; n < 4; ++n) {
      int col = wn * 64 + n * 16 + l15;
#pragma unroll
      for (int rg = 0; rg < 4; ++rg) {
        int row = wm * 64 + m * 16 + lg * 4 + rg;
        op[row * WW + col] = o_[m][n][rg] + xp[row * WW + col];
      }
    }
  }
}

extern "C" void kernel_launch(void* const* d_in, const int* in_sizes, int n_in,
                              void* d_out, int out_size, void* d_ws, size_t ws_size,
                              hipStream_t stream) {
  const float* x  = (const float*)d_in[0];
  const float* Wq = (const float*)d_in[1];
  const float* bq = (const float*)d_in[2];
  const float* Wk = (const float*)d_in[3];
  const float* bk = (const float*)d_in[4];
  const float* Wv = (const float*)d_in[5];
  const float* bv = (const float*)d_in[6];
  float* out = (float*)d_out;

  unsigned short* xbf = (unsigned short*)d_ws;
  unsigned short* qkv = xbf + (size_t)33554432;
  unsigned short* Wp  = qkv + (size_t)3 * 33554432;
  unsigned short* zp  = Wp + (size_t)(8 * 9 * 768 * 32);

  dim3 g0(1024, 2, 4);
  k_prepass<<<g0, 256, 0, stream>>>(x, xbf);
  k_repack<<<6912, 256, 0, stream>>>(Wq, Wk, Wv, Wp, zp);
  k_conv<<<3072, 256, 0, stream>>>(xbf, Wp, zp, bq, bk, bv, qkv);
  k_attn<<<2048, 256, 0, stream>>>(qkv, x, out);
}

// Round 15
// 515.175 us; speedup vs baseline: 1.0173x; 1.0173x over previous
//
#include <hip/hip_runtime.h>

#define BB 8
#define CC 256
#define HH 128
#define WW 128
#define HW (HH*WW)

typedef float f32x4 __attribute__((ext_vector_type(4)));
typedef float f32x16 __attribute__((ext_vector_type(16)));
typedef short s16x8 __attribute__((ext_vector_type(8)));

__device__ inline unsigned short f2bf(float f) {
  union { float f; unsigned int u; } un;
  un.f = f;
  unsigned int u = un.u;
  return (unsigned short)((u + 0x7fffu + ((u >> 16) & 1u)) >> 16);  // RNE
}

__device__ __forceinline__ void gload_lds16(const void* g, void* l) {
  __builtin_amdgcn_global_load_lds(
      (const __attribute__((address_space(1))) unsigned int*)g,
      (__attribute__((address_space(3))) unsigned int*)l, 16, 0, 0);
}

// ---------------- kernel 0: x NCHW f32 -> xbf NHWC bf16 ----------------
__global__ __launch_bounds__(256) void k_prepass(const float* __restrict__ x,
                                                 unsigned short* __restrict__ xbf) {
  __shared__ float tile[64][68];
  int bh = blockIdx.x;
  int b = bh >> 7, h = bh & 127;
  int w0 = blockIdx.y * 64;
  int c0 = blockIdx.z * 64;
  int t = threadIdx.x;
  {
    int c = t >> 2, wq = (t & 3) << 4;
    const float4* src = reinterpret_cast<const float4*>(
        x + (((size_t)(b * CC + c0 + c) * HH + h) * WW + w0 + wq));
    float4 v0 = src[0], v1 = src[1], v2 = src[2], v3 = src[3];
    *reinterpret_cast<float4*>(&tile[c][wq + 0])  = v0;
    *reinterpret_cast<float4*>(&tile[c][wq + 4])  = v1;
    *reinterpret_cast<float4*>(&tile[c][wq + 8])  = v2;
    *reinterpret_cast<float4*>(&tile[c][wq + 12]) = v3;
  }
  __syncthreads();
  {
    int w = t >> 2, cg = (t & 3) << 4;
    unsigned short tmp[16];
#pragma unroll
    for (int i = 0; i < 16; ++i) tmp[i] = f2bf(tile[cg + i][w]);
    unsigned short* dst = xbf + ((size_t)(b * HH + h) * WW + w0 + w) * CC + c0 + cg;
    *reinterpret_cast<int4*>(dst)     = *reinterpret_cast<int4*>(tmp);
    *reinterpret_cast<int4*>(dst + 8) = *reinterpret_cast<int4*>(tmp + 8);
  }
}

// ------- kernel 1: weight repack -> [chunk8][tap9][foc768][ci32] bf16 + zeropage ----
__global__ __launch_bounds__(256) void k_repack(const float* __restrict__ Wq,
                                                const float* __restrict__ Wk,
                                                const float* __restrict__ Wv,
                                                unsigned short* __restrict__ Wp,
                                                unsigned short* __restrict__ zp) {
  if (blockIdx.x == 0 && threadIdx.x < 64) {
    int4 z = {0, 0, 0, 0};
    reinterpret_cast<int4*>(zp)[threadIdx.x] = z;   // 1 KB zero page
  }
  int idx = blockIdx.x * 256 + threadIdx.x;
  if (idx >= 8 * 9 * 768 * 32) return;
  int ci = idx & 31;
  int tmp = idx >> 5;
  int focs = tmp % 768;
  int tmp2 = tmp / 768;
  int tap = tmp2 % 9;
  int chunk = tmp2 / 9;
  int cv = focs >> 8, oc = focs & 255;
  int cin = chunk * 32 + ci;
  const float* Wsrc = (cv == 0) ? Wq : ((cv == 1) ? Wk : Wv);
  Wp[idx] = f2bf(Wsrc[(size_t)(oc * 256 + cin) * 9 + tap]);
}

// ------- kernel 2: fused QKV conv (R13 best: fine-grained sub-clusters, F') ---
// Wave = 32 focs (fq) x 2 rows x 128 w: acc[2 row][4 nt], 3 A-frags/unit
// reused over 8 MFMAs. 4 sub-clusters/unit of 6 MFMA, each fed by the BREAD
// issued one sub-cluster earlier; A(u+1)+2 stage ops at nt0. One barrier per
// chunk, counted vmcnt(6). Swizzle F'(c) = ((c>>1)&3)^((c>>3)&3) both sides.
__global__ __launch_bounds__(256, 2) void k_conv(const unsigned short* __restrict__ xbf,
                                                 const unsigned short* __restrict__ Wp,
                                                 const unsigned short* __restrict__ zp,
                                                 const float* __restrict__ bq,
                                                 const float* __restrict__ bk,
                                                 const float* __restrict__ bv,
                                                 unsigned short* __restrict__ qkv) {
  __shared__ unsigned short xs[2][4][132][32];
  __shared__ float bias_s[128];
  int bid = blockIdx.x;
  int v_ = (bid & 7) * 384 + (bid >> 3);   // bijective XCD swizzle (3072%8==0)
  int mtile = v_ % 6;                      // mtile fast (verified order)
  int bhp = v_ / 6;
  int b = bhp >> 6;
  int h0 = (bhp & 63) * 2;
  int t = threadIdx.x;
  int lane = t & 63, wave = t >> 6;
  int fq = wave;                           // foc-quarter; also staging row
  int l31 = lane & 31, lg1 = lane >> 5;

  if (t < 128) {
    int focs = mtile * 128 + t;
    int cv = focs >> 8, oc = focs & 255;
    const float* bp = (cv == 0) ? bq : ((cv == 1) ? bk : bv);
    bias_s[t] = bp[oc];
  }
  {  // zero the w-halo cells (wc = 0 and 129) of both buffers, all 4 rows
    int cell = t >> 4;
    int bf_ = cell >> 3, r_ = (cell >> 1) & 3;
    int wc_ = (cell & 1) ? 129 : 0;
    *reinterpret_cast<int*>(reinterpret_cast<char*>(&xs[bf_][r_][wc_][0]) + (t & 15) * 4) = 0;
  }

  // staging: lane covers col wc = 1 + l2 + j*16, quarter l4.
  // source oct = l4 ^ F'(wc); j*16 toggles F' by XOR 2 on odd j.
  int l2 = lane >> 2, l4 = lane & 3;
  int wcb = 1 + l2;
  int oswE = l4 ^ (((wcb >> 1) & 3) ^ ((wcb >> 3) & 3));   // even j
  int oswO = oswE ^ 2;                                     // odd j
  int hin = h0 + wave - 1;
  bool inb = ((unsigned)hin < 128u);
  const unsigned short* rowb =
      xbf + ((size_t)(b * HH + (inb ? hin : 0)) * WW + l2) * CC;
  const unsigned short* srowE = rowb + oswE * 8;
  const unsigned short* srowO = rowb + oswO * 8;
  const unsigned short* zsrc = zp + lane * 8;

  const size_t CH_STRIDE = (size_t)9 * 768 * 32;
  const unsigned short* apbase = Wp + (size_t)(mtile * 128 + fq * 32 + l31) * 32 + lg1 * 8;

  auto ALOAD = [&](s16x8 (&Af)[3], const unsigned short* ap, int un) {
    const int ss = un >> 1, kk = un & 1;
#pragma unroll
    for (int rr = 0; rr < 3; ++rr)
      Af[rr] = *reinterpret_cast<const s16x8*>(ap + (rr * 3 + ss) * (768 * 32) + kk * 16);
  };
  auto BREAD = [&](s16x8 (&Bf)[4], const char* xsb, int un, int nt) {
    const int ss = un >> 1, kk = un & 1;
    const int col = nt * 32 + l31 + ss;     // 0..129
    const int pslot = (kk * 2 + lg1) ^ (((col >> 1) & 3) ^ ((col >> 3) & 3));
#pragma unroll
    for (int rin = 0; rin < 4; ++rin)
      Bf[rin] = *reinterpret_cast<const s16x8*>(
          xsb + rin * (132 * 64) + col * 64 + pslot * 16);
  };

  f32x16 acc[2][4] = {};   // [row][nt]
  s16x8 Afb[2][3];         // A dbuf [unit&1][rr]
  s16x8 Bfb[2][4];         // B sub-cluster dbuf [nt&1][rin]

  // ---- prologue: stage chunk 0; A(u0); counted wait; barrier; B(u0,nt0)
  {
    char* d0 = reinterpret_cast<char*>(&xs[0][wave][1][0]);
    if (inb) {
#pragma unroll
      for (int j = 0; j < 8; ++j)
        gload_lds16(((j & 1) ? srowO : srowE) + j * (16 * CC), d0 + j * 1024);
    } else {
#pragma unroll
      for (int j = 0; j < 8; ++j) gload_lds16(zsrc, d0 + j * 1024);
    }
  }
  ALOAD(Afb[0], apbase, 0);
  asm volatile("s_waitcnt vmcnt(3)" ::: "memory");   // 8 stage retired (3 A newer)
  __builtin_amdgcn_s_barrier();
  BREAD(Bfb[0], reinterpret_cast<const char*>(&xs[0][0][0][0]), 0, 0);

  for (int chunk = 0; chunk < 8; ++chunk) {
    const int buf = chunk & 1;
    const unsigned short* ap_cur = apbase + chunk * CH_STRIDE;
    const char* xsb = reinterpret_cast<const char*>(&xs[buf][0][0][0]);

#pragma unroll
    for (int u = 0; u < 6; ++u) {
#pragma unroll
      for (int nt = 0; nt < 4; ++nt) {
        // ---- issue region (feeds the NEXT sub-cluster / unit)
        if (nt < 3) {
          BREAD(Bfb[(nt + 1) & 1], xsb, u, nt + 1);
        } else if (u < 5) {
          BREAD(Bfb[0], xsb, u + 1, 0);
        }
        if (nt == 0) {
          if (u < 5) ALOAD(Afb[(u + 1) & 1], ap_cur, u + 1);
          else if (chunk < 7) ALOAD(Afb[0], ap_cur + CH_STRIDE, 0);
          if (u < 4 && chunk < 7) {
            char* dstg = reinterpret_cast<char*>(&xs[buf ^ 1][wave][1][0]);
            int jA = 2 * u, jB = 2 * u + 1;     // jA even, jB odd
            if (inb) {
              gload_lds16(srowE + (size_t)(chunk + 1) * 32 + jA * (16 * CC), dstg + jA * 1024);
              gload_lds16(srowO + (size_t)(chunk + 1) * 32 + jB * (16 * CC), dstg + jB * 1024);
            } else {
              gload_lds16(zsrc, dstg + jA * 1024);
              gload_lds16(zsrc, dstg + jB * 1024);
            }
          }
        }
        __builtin_amdgcn_sched_barrier(0);
        // ---- sub-cluster: 6 MFMA (3 rr x 2 row) on Afb[u&1], Bfb[nt&1]
        __builtin_amdgcn_s_setprio(1);
#pragma unroll
        for (int rr = 0; rr < 3; ++rr)
#pragma unroll
          for (int row = 0; row < 2; ++row)
            acc[row][nt] = __builtin_amdgcn_mfma_f32_32x32x16_bf16(
                Afb[u & 1][rr], Bfb[nt & 1][row + rr], acc[row][nt], 0, 0, 0);
        __builtin_amdgcn_s_setprio(0);
        __builtin_amdgcn_sched_barrier(0);
      }
    }
    // ---- chunk boundary: counted drain (6 A-loads issued after last stage)
    if (chunk < 7) {
      asm volatile("s_waitcnt vmcnt(6)" ::: "memory");
      __builtin_amdgcn_s_barrier();
      asm volatile("" ::: "memory");
      BREAD(Bfb[0], reinterpret_cast<const char*>(&xs[buf ^ 1][0][0][0]), 0, 0);
    }
  }

  // epilogue: bias, relu (q,k), store bf16. D-layout 32x32:
  // col = lane&31, row = (reg&3) + 8*(reg>>2) + 4*(lane>>5)
#pragma unroll
  for (int row = 0; row < 2; ++row) {
#pragma unroll
    for (int nt = 0; nt < 4; ++nt) {
      int wcol = nt * 32 + l31;
      int h = h0 + row;
#pragma unroll
      for (int reg = 0; reg < 16; ++reg) {
        int rloc = (reg & 3) + 8 * (reg >> 2) + 4 * lg1;
        int floc = fq * 32 + rloc;
        float vv = acc[row][nt][reg] + bias_s[floc];
        int focs = mtile * 128 + floc;
        if (focs < 512) vv = fmaxf(vv, 0.0f);      // relu for q,k
        int cv = focs >> 8, oc = focs & 255;
        qkv[(size_t)(cv * 2048 + b * 256 + oc) * HW + h * WW + wcol] = f2bf(vv);
      }
    }
  }
}

// ---------------- kernel 3: per-(b,c) attention -------------------------------
// al aliases kt (kt dead after QK^T; barriers order last read before write).
#define PADA 136
__global__ __launch_bounds__(256) void k_attn(const unsigned short* __restrict__ qkv,
                                              const float* __restrict__ x,
                                              float* __restrict__ out) {
  __shared__ unsigned short kt[128][PADA];
  __shared__ unsigned short vt[128][PADA];
  __shared__ float red[8];
  unsigned short (*al)[PADA] = kt;    // alias: reuse kt after QK^T
  int bc = blockIdx.x;
  const unsigned short* qp = qkv + (size_t)bc * HW;
  const unsigned short* kp = qkv + (size_t)(2048 + bc) * HW;
  const unsigned short* vp = qkv + (size_t)(4096 + bc) * HW;
  int t = threadIdx.x;
  for (int g = t; g < HW; g += 256) {
    int row = g >> 7, col = g & 127;
    kt[col][row] = kp[g];
    vt[col][row] = vp[g];
  }
  __syncthreads();
  int lane = t & 63, wave = t >> 6;
  int wm = wave >> 1, wn = wave & 1;
  int l15 = lane & 15, lg = lane >> 4;
  f32x4 acc[4][4] = {};
#pragma unroll
  for (int kk = 0; kk < 4; ++kk) {
    s16x8 af[4], bfr[4];
#pragma unroll
    for (int m = 0; m < 4; ++m)
      af[m] = *reinterpret_cast<const s16x8*>(qp + (size_t)(wm * 64 + m * 16 + l15) * WW + kk * 32 + lg * 8);
#pragma unroll
    for (int n = 0; n < 4; ++n)
      bfr[n] = *reinterpret_cast<const s16x8*>(&kt[wn * 64 + n * 16 + l15][kk * 32 + lg * 8]);
#pragma unroll
    for (int m = 0; m < 4; ++m)
#pragma unroll
      for (int n = 0; n < 4; ++n)
        acc[m][n] = __builtin_amdgcn_mfma_f32_16x16x32_bf16(af[m], bfr[n], acc[m][n], 0, 0, 0);
  }
  float lm = -3.0e38f;
#pragma unroll
  for (int m = 0; m < 4; ++m)
#pragma unroll
    for (int n = 0; n < 4; ++n)
#pragma unroll
      for (int rg = 0; rg < 4; ++rg)
        lm = fmaxf(lm, acc[m][n][rg]);
  for (int off = 32; off > 0; off >>= 1) lm = fmaxf(lm, __shfl_xor(lm, off));
  if (lane == 0) red[wave] = lm;
  __syncthreads();   // also orders last kt read before al writes below
  float M = fmaxf(fmaxf(red[0], red[1]), fmaxf(red[2], red[3]));
  float ls = 0.0f;
#pragma unroll
  for (int m = 0; m < 4; ++m)
#pragma unroll
    for (int n = 0; n < 4; ++n)
#pragma unroll
      for (int rg = 0; rg < 4; ++rg)
        ls += __expf(acc[m][n][rg] - M);
  for (int off = 32; off > 0; off >>= 1) ls += __shfl_xor(ls, off);
  if (lane == 0) red[4 + wave] = ls;
  __syncthreads();
  float inv = 1.0f / (red[4] + red[5] + red[6] + red[7]);
#pragma unroll
  for (int m = 0; m < 4; ++m) {
#pragma unroll
    for (int n = 0; n < 4; ++n) {
      int col = wn * 64 + n * 16 + l15;
#pragma unroll
      for (int rg = 0; rg < 4; ++rg) {
        int row = wm * 64 + m * 16 + lg * 4 + rg;
        al[row][col] = f2bf(__expf(acc[m][n][rg] - M) * inv);
      }
    }
  }
  __syncthreads();
  f32x4 o_[4][4] = {};
#pragma unroll
  for (int kk = 0; kk < 4; ++kk) {
    s16x8 af[4], bfr[4];
#pragma unroll
    for (int m = 0; m < 4; ++m)
      af[m] = *reinterpret_cast<const s16x8*>(&al[wm * 64 + m * 16 + l15][kk * 32 + lg * 8]);
#pragma unroll
    for (int n = 0; n < 4; ++n)
      bfr[n] = *reinterpret_cast<const s16x8*>(&vt[wn * 64 + n * 16 + l15][kk * 32 + lg * 8]);
#pragma unroll
    for (int m = 0; m < 4; ++m)
#pragma unroll
      for (int n = 0; n < 4; ++n)
        o_[m][n] = __builtin_amdgcn_mfma_f32_16x16x32_bf16(af[m], bfr[n], o_[m][n], 0, 0, 0);
  }
  const float* xp = x + (size_t)bc * HW;
  float* op = out + (size_t)bc * HW;
#pragma unroll
  for (int m = 0; m < 4; ++m) {
#pragma unroll
    for (int n = 0; n < 4; ++n) {
      int col = wn * 64 + n * 16 + l15;
#pragma unroll
      for (int rg = 0; rg < 4; ++rg) {
        int row = wm * 64 + m * 16 + lg * 4 + rg;
        op[row * WW + col] = o_[m][n][rg] + xp[row * WW + col];
      }
    }
  }
}

extern "C" void kernel_launch(void* const* d_in, const int* in_sizes, int n_in,
                              void* d_out, int out_size, void* d_ws, size_t ws_size,
                              hipStream_t stream) {
  const float* x  = (const float*)d_in[0];
  const float* Wq = (const float*)d_in[1];
  const float* bq = (const float*)d_in[2];
  const float* Wk = (const float*)d_in[3];
  const float* bk = (const float*)d_in[4];
  const float* Wv = (const float*)d_in[5];
  const float* bv = (const float*)d_in[6];
  float* out = (float*)d_out;

  unsigned short* xbf = (unsigned short*)d_ws;
  unsigned short* qkv = xbf + (size_t)33554432;
  unsigned short* Wp  = qkv + (size_t)3 * 33554432;
  unsigned short* zp  = Wp + (size_t)(8 * 9 * 768 * 32);

  dim3 g0(1024, 2, 4);
  k_prepass<<<g0, 256, 0, stream>>>(x, xbf);
  k_repack<<<6912, 256, 0, stream>>>(Wq, Wk, Wv, Wp, zp);
  k_conv<<<3072, 256, 0, stream>>>(xbf, Wp, zp, bq, bk, bv, qkv);
  k_attn<<<2048, 256, 0, stream>>>(qkv, x, out);
}